// Round 1
// baseline (1745.189 us; speedup 1.0000x reference)
//
#include <hip/hip_runtime.h>
#include <hip/hip_bf16.h>
#include <stdint.h>

typedef __bf16 bf16x8_t __attribute__((ext_vector_type(8)));
typedef float  f32x4_t  __attribute__((ext_vector_type(8/2)));

// async global->LDS, 16B per lane. LDS dest must be wave-uniform base + lane*16.
__device__ __forceinline__ void gld_lds16(const void* g, void* l) {
    __builtin_amdgcn_global_load_lds(
        (const __attribute__((address_space(1))) uint32_t*)g,
        (__attribute__((address_space(3))) uint32_t*)l, 16, 0, 0);
}

// ---------------------------------------------------------------- conv1 (fp32 vector)
// x[16,100,64,1] -> y[16,92,56,256] bf16, relu. block=(b,oh), thread=oc.
__global__ __launch_bounds__(256) void k_conv1(
    const float* __restrict__ x, const float* __restrict__ w,
    const float* __restrict__ bias, __hip_bfloat16* __restrict__ y)
{
    const int b  = blockIdx.x / 92;
    const int oh = blockIdx.x % 92;
    const int oc = threadIdx.x;
    float wr[81];
#pragma unroll
    for (int t = 0; t < 81; ++t) wr[t] = w[t * 256 + oc];
    const float bs = bias[oc];
    const float* xb = x + (b * 100 + oh) * 64;
    __hip_bfloat16* yb = y + ((b * 92 + oh) * 56) * 256 + oc;
    for (int owg = 0; owg < 56; owg += 4) {
        float a0 = bs, a1 = bs, a2 = bs, a3 = bs;
#pragma unroll
        for (int kh = 0; kh < 9; ++kh) {
            const float* xr = xb + kh * 64 + owg;   // uniform -> s_load
            float xv[12];
#pragma unroll
            for (int t = 0; t < 12; ++t) xv[t] = xr[t];
#pragma unroll
            for (int kw = 0; kw < 9; ++kw) {
                const float wv = wr[kh * 9 + kw];
                a0 = fmaf(xv[kw + 0], wv, a0);
                a1 = fmaf(xv[kw + 1], wv, a1);
                a2 = fmaf(xv[kw + 2], wv, a2);
                a3 = fmaf(xv[kw + 3], wv, a3);
            }
        }
        yb[(owg + 0) * 256] = __float2bfloat16(fmaxf(a0, 0.f));
        yb[(owg + 1) * 256] = __float2bfloat16(fmaxf(a1, 0.f));
        yb[(owg + 2) * 256] = __float2bfloat16(fmaxf(a2, 0.f));
        yb[(owg + 3) * 256] = __float2bfloat16(fmaxf(a3, 0.f));
    }
}

// ---------------------------------------------------------------- pc_w transpose+cast
// pc_w[k=(kh,kw,ic)][oc] fp32 -> wt[oc][k] bf16. writes coalesced; reads bounce off L2.
__global__ __launch_bounds__(256) void k_wt(
    const float* __restrict__ w, __hip_bfloat16* __restrict__ wt)
{
    const int idx = blockIdx.x * 256 + threadIdx.x;   // < 256*20736
    const int oc  = idx / 20736;
    const int k   = idx - oc * 20736;
    wt[idx] = __float2bfloat16(w[k * 256 + oc]);
}

// ---------------------------------------------------------------- PC conv as MFMA GEMM
// M=16128 (b,oh,ow), N=256 (oc), K=20736. 128x128 tile, BK=32, K-split x3.
__global__ __launch_bounds__(256) void k_pcconv(
    const __hip_bfloat16* __restrict__ y,
    const __hip_bfloat16* __restrict__ wt,
    float* __restrict__ pout0, float* __restrict__ pout1, float* __restrict__ pout2)
{
    __shared__ __hip_bfloat16 lA[128 * 32];
    __shared__ __hip_bfloat16 lB[128 * 32];
    float* __restrict__ p = (blockIdx.z == 0) ? pout0 : (blockIdx.z == 1 ? pout1 : pout2);

    const int tid  = threadIdx.x;
    const int m0   = blockIdx.x * 128;
    const int n0   = blockIdx.y * 128;
    const int kc0  = blockIdx.z * 216;
    const int quad = tid & 3;
    const int trow = tid >> 2;

    int ybase[2];
#pragma unroll
    for (int r = 0; r < 2; ++r) {
        const int m  = m0 + r * 64 + trow;
        const int b  = m / 1008;            // 42*24
        const int rm = m - b * 1008;
        const int oh = rm / 24;
        const int ow = rm - oh * 24;
        ybase[r] = ((b * 92 + 2 * oh) * 56 + 2 * ow) * 256 + quad * 8;
    }
    int wbase[2];
#pragma unroll
    for (int r = 0; r < 2; ++r)
        wbase[r] = (n0 + r * 64 + trow) * 20736 + quad * 8;

    f32x4_t acc[4][4];
#pragma unroll
    for (int mi = 0; mi < 4; ++mi)
#pragma unroll
        for (int ni = 0; ni < 4; ++ni)
            acc[mi][ni] = (f32x4_t){0.f, 0.f, 0.f, 0.f};

    const int wv   = tid >> 6;
    const int lane = tid & 63;
    const int mw   = (wv >> 1) * 64;
    const int nw   = (wv & 1) * 64;
    const int lr   = lane & 15;
    const int lq   = lane >> 4;

    for (int kc = kc0; kc < kc0 + 216; ++kc) {
        const int k0   = kc * 32;
        const int khw  = k0 >> 8;
        const int ic0  = k0 & 255;
        const int kh   = khw / 9;
        const int kw2  = khw - kh * 9;
        const int aoff = (kh * 56 + kw2) * 256 + ic0;
        __syncthreads();
#pragma unroll
        for (int r = 0; r < 2; ++r)
            gld_lds16(y + ybase[r] + aoff, &lA[r * 2048 + tid * 8]);
#pragma unroll
        for (int r = 0; r < 2; ++r)
            gld_lds16(wt + wbase[r] + k0, &lB[r * 2048 + tid * 8]);
        __builtin_amdgcn_s_waitcnt(0);
        __syncthreads();
        bf16x8_t af[4], bfr[4];
#pragma unroll
        for (int mi = 0; mi < 4; ++mi)
            af[mi] = *(const bf16x8_t*)&lA[(mw + mi * 16 + lr) * 32 + lq * 8];
#pragma unroll
        for (int ni = 0; ni < 4; ++ni)
            bfr[ni] = *(const bf16x8_t*)&lB[(nw + ni * 16 + lr) * 32 + lq * 8];
#pragma unroll
        for (int mi = 0; mi < 4; ++mi)
#pragma unroll
            for (int ni = 0; ni < 4; ++ni)
                acc[mi][ni] = __builtin_amdgcn_mfma_f32_16x16x32_bf16(
                    af[mi], bfr[ni], acc[mi][ni], 0, 0, 0);
    }
#pragma unroll
    for (int mi = 0; mi < 4; ++mi)
#pragma unroll
        for (int ni = 0; ni < 4; ++ni) {
            const int col = n0 + nw + ni * 16 + lr;
#pragma unroll
            for (int rr = 0; rr < 4; ++rr) {
                const int row = m0 + mw + mi * 16 + lq * 4 + rr;
                p[row * 256 + col] = acc[mi][ni][rr];
            }
        }
}

// ---------------------------------------------------------------- squash (sums K-splits)
// u[b,i,k] = squash over k=0..7 of (p0+p1+p2+bias). In-place into p0 is safe per-thread.
__global__ __launch_bounds__(256) void k_squash(
    const float* p0, const float* p1, const float* p2,
    const float* __restrict__ bias, float* u)
{
    const int g = blockIdx.x * 256 + threadIdx.x;   // < 516096
    const int base = g * 8;
    const int cb = (g & 31) * 8;
    float v[8]; float sq = 0.f;
    const float4 a0 = *(const float4*)(p0 + base), a1 = *(const float4*)(p0 + base + 4);
    const float4 b0 = *(const float4*)(p1 + base), b1 = *(const float4*)(p1 + base + 4);
    const float4 c0 = *(const float4*)(p2 + base), c1 = *(const float4*)(p2 + base + 4);
    v[0] = a0.x + b0.x + c0.x + bias[cb + 0];
    v[1] = a0.y + b0.y + c0.y + bias[cb + 1];
    v[2] = a0.z + b0.z + c0.z + bias[cb + 2];
    v[3] = a0.w + b0.w + c0.w + bias[cb + 3];
    v[4] = a1.x + b1.x + c1.x + bias[cb + 4];
    v[5] = a1.y + b1.y + c1.y + bias[cb + 5];
    v[6] = a1.z + b1.z + c1.z + bias[cb + 6];
    v[7] = a1.w + b1.w + c1.w + bias[cb + 7];
#pragma unroll
    for (int t = 0; t < 8; ++t) sq += v[t] * v[t];
    const float sc = sq / ((1.f + sq) * sqrtf(sq + 1e-7f));
#pragma unroll
    for (int t = 0; t < 8; ++t) u[base + t] = v[t] * sc;
}

// ---------------------------------------------------------------- routing iteration
// Recompute u_hat from W (streams 165MB). b-logit = vsum . u_hat (vsum = sum of prev v).
// 4 lanes per capsule i, lane q owns dims [4q,4q+4). grid = 16 b x 56 chunks.
__global__ __launch_bounds__(256) void k_route(
    const float* __restrict__ u, const float* __restrict__ W,
    const float* __restrict__ vsum, float* __restrict__ sp)
{
    const int b     = blockIdx.x / 56;
    const int chunk = blockIdx.x % 56;
    const int tid   = threadIdx.x;
    const int lane  = tid & 63;
    const int wv    = tid >> 6;
    const int q     = lane & 3;
    const int ig    = lane >> 2;

    float vs[10][4];
#pragma unroll
    for (int j = 0; j < 10; ++j) {
        const float4 t = *(const float4*)(vsum + (b * 10 + j) * 16 + q * 4);
        vs[j][0] = t.x; vs[j][1] = t.y; vs[j][2] = t.z; vs[j][3] = t.w;
    }
    float acc[10][4];
#pragma unroll
    for (int j = 0; j < 10; ++j)
#pragma unroll
        for (int t = 0; t < 4; ++t) acc[j][t] = 0.f;

    const int ib = chunk * 576 + wv * 16 + ig;
    for (int ps = 0; ps < 9; ++ps) {
        const int i = ib + ps * 64;
        const float* up = u + (b * 32256 + i) * 8;
        const float4 u0 = *(const float4*)up;
        const float4 u1 = *(const float4*)(up + 4);
        float uh[10][4], logit[10];
#pragma unroll
        for (int j = 0; j < 10; ++j) {
            const float* wp = W + ((long)(j * 32256 + i)) * 128 + q * 32;
            float lg = 0.f;
#pragma unroll
            for (int t = 0; t < 4; ++t) {
                const float4 wa = *(const float4*)(wp + t * 8);
                const float4 wb = *(const float4*)(wp + t * 8 + 4);
                float h = wa.x * u0.x + wa.y * u0.y + wa.z * u0.z + wa.w * u0.w
                        + wb.x * u1.x + wb.y * u1.y + wb.z * u1.z + wb.w * u1.w;
                uh[j][t] = h;
                lg = fmaf(vs[j][t], h, lg);
            }
            lg += __shfl_xor(lg, 1);
            lg += __shfl_xor(lg, 2);
            logit[j] = lg;
        }
        float mx = logit[0];
#pragma unroll
        for (int j = 1; j < 10; ++j) mx = fmaxf(mx, logit[j]);
        float den = 0.f, e[10];
#pragma unroll
        for (int j = 0; j < 10; ++j) { e[j] = __expf(logit[j] - mx); den += e[j]; }
        const float inv = __builtin_amdgcn_rcpf(den);
#pragma unroll
        for (int j = 0; j < 10; ++j) {
            const float c = e[j] * inv;
#pragma unroll
            for (int t = 0; t < 4; ++t) acc[j][t] = fmaf(c, uh[j][t], acc[j][t]);
        }
    }
    // reduce the 16 capsule-slots of this wave, then one atomic per (j,t) from lanes 0..3
#pragma unroll
    for (int j = 0; j < 10; ++j)
#pragma unroll
        for (int t = 0; t < 4; ++t) {
            float v2 = acc[j][t];
            v2 += __shfl_xor(v2, 4);
            v2 += __shfl_xor(v2, 8);
            v2 += __shfl_xor(v2, 16);
            v2 += __shfl_xor(v2, 32);
            if (lane < 4) atomicAdd(&sp[(b * 10 + j) * 16 + q * 4 + t], v2);
        }
}

// ---------------------------------------------------------------- v = squash(s); vsum += v
__global__ void k_finish(const float* __restrict__ sp, float* __restrict__ vsum,
                         float* __restrict__ out, const int fin)
{
    const int t = threadIdx.x;
    if (t >= 160) return;          // t = b*10 + j
    const float* s = sp + t * 16;
    float sv[16]; float sq = 0.f;
#pragma unroll
    for (int d = 0; d < 16; ++d) { sv[d] = s[d]; sq += sv[d] * sv[d]; }
    const float sc = sq / ((1.f + sq) * sqrtf(sq + 1e-7f));
    if (fin) {
#pragma unroll
        for (int d = 0; d < 16; ++d) out[t * 16 + d] = sv[d] * sc;
    } else {
        float* vp = vsum + t * 16;
#pragma unroll
        for (int d = 0; d < 16; ++d) vp[d] += sv[d] * sc;
    }
}

extern "C" void kernel_launch(void* const* d_in, const int* in_sizes, int n_in,
                              void* d_out, int out_size, void* d_ws, size_t ws_size,
                              hipStream_t stream)
{
    const float* x   = (const float*)d_in[0];
    const float* c1w = (const float*)d_in[1];
    const float* c1b = (const float*)d_in[2];
    const float* pcw = (const float*)d_in[3];
    const float* pcb = (const float*)d_in[4];
    const float* cW  = (const float*)d_in[5];
    float* out = (float*)d_out;

    char* ws = (char*)d_ws;
    __hip_bfloat16* y  = (__hip_bfloat16*)(ws);                 // 42,205,184 B
    __hip_bfloat16* wt = (__hip_bfloat16*)(ws + 42205184);      // 10,616,832 B
    float* p0   = (float*)(ws + 52822016);                      // 16,515,072 B
    float* p1   = (float*)(ws + 69337088);                      // 16,515,072 B
    float* p2   = (float*)(ws + 85852160);                      // 16,515,072 B
    float* sp   = (float*)(ws + 102367232);                     // 3*2560*4 B
    float* vsum = (float*)(ws + 102397952);                     // 2560*4 B

    // zero s-partials + vsum (ws is poisoned 0xAA before every call)
    hipMemsetAsync(sp, 0, (3 * 2560 + 2560) * 4, stream);

    k_conv1<<<16 * 92, 256, 0, stream>>>(x, c1w, c1b, y);
    k_wt<<<20736, 256, 0, stream>>>(pcw, wt);
    k_pcconv<<<dim3(126, 2, 3), 256, 0, stream>>>(y, wt, p0, p1, p2);
    k_squash<<<2016, 256, 0, stream>>>(p0, p1, p2, pcb, p0);   // u in-place into p0
    for (int it = 0; it < 3; ++it) {
        k_route<<<896, 256, 0, stream>>>(p0, cW, vsum, sp + it * 2560);
        k_finish<<<1, 256, 0, stream>>>(sp + it * 2560, vsum, out, it == 2 ? 1 : 0);
    }
}

// Round 2
// 1224.555 us; speedup vs baseline: 1.4252x; 1.4252x over previous
//
#include <hip/hip_runtime.h>
#include <hip/hip_bf16.h>
#include <hip/hip_fp16.h>
#include <stdint.h>

typedef __bf16 bf16x8_t __attribute__((ext_vector_type(8)));
typedef float  f32x4_t  __attribute__((ext_vector_type(4)));

// async global->LDS, 16B per lane. LDS dest must be wave-uniform base + lane*16.
__device__ __forceinline__ void gld_lds16(const void* g, void* l) {
    __builtin_amdgcn_global_load_lds(
        (const __attribute__((address_space(1))) uint32_t*)g,
        (__attribute__((address_space(3))) uint32_t*)l, 16, 0, 0);
}

// ---------------------------------------------------------------- conv1 (fp32 vector)
// x[16,100,64,1] -> y[16,92,56,256] bf16, relu. block=(b,oh), thread=oc.
__global__ __launch_bounds__(256) void k_conv1(
    const float* __restrict__ x, const float* __restrict__ w,
    const float* __restrict__ bias, __hip_bfloat16* __restrict__ y)
{
    const int b  = blockIdx.x / 92;
    const int oh = blockIdx.x % 92;
    const int oc = threadIdx.x;
    float wr[81];
#pragma unroll
    for (int t = 0; t < 81; ++t) wr[t] = w[t * 256 + oc];
    const float bs = bias[oc];
    const float* xb = x + (b * 100 + oh) * 64;
    __hip_bfloat16* yb = y + ((b * 92 + oh) * 56) * 256 + oc;
    for (int owg = 0; owg < 56; owg += 4) {
        float a0 = bs, a1 = bs, a2 = bs, a3 = bs;
#pragma unroll
        for (int kh = 0; kh < 9; ++kh) {
            const float* xr = xb + kh * 64 + owg;   // uniform -> s_load
            float xv[12];
#pragma unroll
            for (int t = 0; t < 12; ++t) xv[t] = xr[t];
#pragma unroll
            for (int kw = 0; kw < 9; ++kw) {
                const float wv = wr[kh * 9 + kw];
                a0 = fmaf(xv[kw + 0], wv, a0);
                a1 = fmaf(xv[kw + 1], wv, a1);
                a2 = fmaf(xv[kw + 2], wv, a2);
                a3 = fmaf(xv[kw + 3], wv, a3);
            }
        }
        yb[(owg + 0) * 256] = __float2bfloat16(fmaxf(a0, 0.f));
        yb[(owg + 1) * 256] = __float2bfloat16(fmaxf(a1, 0.f));
        yb[(owg + 2) * 256] = __float2bfloat16(fmaxf(a2, 0.f));
        yb[(owg + 3) * 256] = __float2bfloat16(fmaxf(a3, 0.f));
    }
}

// ---------------------------------------------------------------- pc_w transpose+cast
__global__ __launch_bounds__(256) void k_wt(
    const float* __restrict__ w, __hip_bfloat16* __restrict__ wt)
{
    const int idx = blockIdx.x * 256 + threadIdx.x;   // < 256*20736
    const int oc  = idx / 20736;
    const int k   = idx - oc * 20736;
    wt[idx] = __float2bfloat16(w[k * 256 + oc]);
}

// ---------------------------------------------------------------- PC conv as MFMA GEMM
// M=16128 (b,oh,ow), N=256 (oc), K=20736. 128x128 tile, BK=32, K-split x3.
__global__ __launch_bounds__(256) void k_pcconv(
    const __hip_bfloat16* __restrict__ y,
    const __hip_bfloat16* __restrict__ wt,
    float* __restrict__ pout0, float* __restrict__ pout1, float* __restrict__ pout2)
{
    __shared__ __hip_bfloat16 lA[128 * 32];
    __shared__ __hip_bfloat16 lB[128 * 32];
    float* __restrict__ p = (blockIdx.z == 0) ? pout0 : (blockIdx.z == 1 ? pout1 : pout2);

    const int tid  = threadIdx.x;
    const int m0   = blockIdx.x * 128;
    const int n0   = blockIdx.y * 128;
    const int kc0  = blockIdx.z * 216;
    const int quad = tid & 3;
    const int trow = tid >> 2;

    int ybase[2];
#pragma unroll
    for (int r = 0; r < 2; ++r) {
        const int m  = m0 + r * 64 + trow;
        const int b  = m / 1008;            // 42*24
        const int rm = m - b * 1008;
        const int oh = rm / 24;
        const int ow = rm - oh * 24;
        ybase[r] = ((b * 92 + 2 * oh) * 56 + 2 * ow) * 256 + quad * 8;
    }
    int wbase[2];
#pragma unroll
    for (int r = 0; r < 2; ++r)
        wbase[r] = (n0 + r * 64 + trow) * 20736 + quad * 8;

    f32x4_t acc[4][4];
#pragma unroll
    for (int mi = 0; mi < 4; ++mi)
#pragma unroll
        for (int ni = 0; ni < 4; ++ni)
            acc[mi][ni] = (f32x4_t){0.f, 0.f, 0.f, 0.f};

    const int wv   = tid >> 6;
    const int lane = tid & 63;
    const int mw   = (wv >> 1) * 64;
    const int nw   = (wv & 1) * 64;
    const int lr   = lane & 15;
    const int lq   = lane >> 4;

    for (int kc = kc0; kc < kc0 + 216; ++kc) {
        const int k0   = kc * 32;
        const int khw  = k0 >> 8;
        const int ic0  = k0 & 255;
        const int kh   = khw / 9;
        const int kw2  = khw - kh * 9;
        const int aoff = (kh * 56 + kw2) * 256 + ic0;
        __syncthreads();
#pragma unroll
        for (int r = 0; r < 2; ++r)
            gld_lds16(y + ybase[r] + aoff, &lA[r * 2048 + tid * 8]);
#pragma unroll
        for (int r = 0; r < 2; ++r)
            gld_lds16(wt + wbase[r] + k0, &lB[r * 2048 + tid * 8]);
        __builtin_amdgcn_s_waitcnt(0);
        __syncthreads();
        bf16x8_t af[4], bfr[4];
#pragma unroll
        for (int mi = 0; mi < 4; ++mi)
            af[mi] = *(const bf16x8_t*)&lA[(mw + mi * 16 + lr) * 32 + lq * 8];
#pragma unroll
        for (int ni = 0; ni < 4; ++ni)
            bfr[ni] = *(const bf16x8_t*)&lB[(nw + ni * 16 + lr) * 32 + lq * 8];
#pragma unroll
        for (int mi = 0; mi < 4; ++mi)
#pragma unroll
            for (int ni = 0; ni < 4; ++ni)
                acc[mi][ni] = __builtin_amdgcn_mfma_f32_16x16x32_bf16(
                    af[mi], bfr[ni], acc[mi][ni], 0, 0, 0);
    }
#pragma unroll
    for (int mi = 0; mi < 4; ++mi)
#pragma unroll
        for (int ni = 0; ni < 4; ++ni) {
            const int col = n0 + nw + ni * 16 + lr;
#pragma unroll
            for (int rr = 0; rr < 4; ++rr) {
                const int row = m0 + mw + mi * 16 + lq * 4 + rr;
                p[row * 256 + col] = acc[mi][ni][rr];
            }
        }
}

// ---------------------------------------------------------------- squash (sums K-splits)
__global__ __launch_bounds__(256) void k_squash(
    const float* p0, const float* p1, const float* p2,
    const float* __restrict__ bias, float* u)
{
    const int g = blockIdx.x * 256 + threadIdx.x;   // < 516096
    const int base = g * 8;
    const int cb = (g & 31) * 8;
    float v[8]; float sq = 0.f;
    const float4 a0 = *(const float4*)(p0 + base), a1 = *(const float4*)(p0 + base + 4);
    const float4 b0 = *(const float4*)(p1 + base), b1 = *(const float4*)(p1 + base + 4);
    const float4 c0 = *(const float4*)(p2 + base), c1 = *(const float4*)(p2 + base + 4);
    v[0] = a0.x + b0.x + c0.x + bias[cb + 0];
    v[1] = a0.y + b0.y + c0.y + bias[cb + 1];
    v[2] = a0.z + b0.z + c0.z + bias[cb + 2];
    v[3] = a0.w + b0.w + c0.w + bias[cb + 3];
    v[4] = a1.x + b1.x + c1.x + bias[cb + 4];
    v[5] = a1.y + b1.y + c1.y + bias[cb + 5];
    v[6] = a1.z + b1.z + c1.z + bias[cb + 6];
    v[7] = a1.w + b1.w + c1.w + bias[cb + 7];
#pragma unroll
    for (int t = 0; t < 8; ++t) sq += v[t] * v[t];
    const float sc = sq / ((1.f + sq) * sqrtf(sq + 1e-7f));
#pragma unroll
    for (int t = 0; t < 8; ++t) u[base + t] = v[t] * sc;
}

// ---------------------------------------------------------------- u_hat precompute (fp16)
// uh[((b*32256+i)*4+q)*40 + j*4 + d'] = sum_k W[j,i,q*4+d',k] * u[b,i,k]
// thread = (i,q). W read exactly once (165MB); u served from L1/L2.
__global__ __launch_bounds__(256) void k_uhat(
    const float* __restrict__ u, const float* __restrict__ W, __half* __restrict__ uh)
{
    const int tid = blockIdx.x * 256 + threadIdx.x;   // < 129024
    const int q = tid & 3;
    const int i = tid >> 2;
    for (int j = 0; j < 10; ++j) {
        const float* wp = W + (((long)j * 32256 + i) * 16 + q * 4) * 8;
        float4 w[8];
#pragma unroll
        for (int t = 0; t < 8; ++t) w[t] = *(const float4*)(wp + t * 4);
#pragma unroll 4
        for (int b = 0; b < 16; ++b) {
            const float* up = u + (b * 32256 + i) * 8;
            const float4 u0 = *(const float4*)up;
            const float4 u1 = *(const float4*)(up + 4);
            union { __half h[4]; uint2 u2; } pk;
#pragma unroll
            for (int d = 0; d < 4; ++d) {
                const float4 a = w[2 * d], c = w[2 * d + 1];
                float h = a.x * u0.x + a.y * u0.y + a.z * u0.z + a.w * u0.w
                        + c.x * u1.x + c.y * u1.y + c.z * u1.z + c.w * u1.w;
                pk.h[d] = __float2half(h);
            }
            *(uint2*)(uh + (((long)b * 32256 + i) * 4 + q) * 40 + j * 4) = pk.u2;
        }
    }
}

// ---------------------------------------------------------------- routing iteration
// Streams uh (165MB fp16) once. logit = vsum . u_hat; softmax over j; s += c*u_hat.
// 4 lanes per capsule i (lane q owns dims [4q,4q+4)). grid = 16 b x 56 chunks.
__global__ __launch_bounds__(256) void k_route2(
    const __half* __restrict__ uh, const float* __restrict__ vsum,
    float* __restrict__ sp)
{
    const int b     = blockIdx.x / 56;
    const int chunk = blockIdx.x % 56;
    const int tid   = threadIdx.x;
    const int lane  = tid & 63;
    const int wv    = tid >> 6;
    const int q     = lane & 3;
    const int ig    = lane >> 2;

    float vs[10][4];
#pragma unroll
    for (int j = 0; j < 10; ++j) {
        const float4 t = *(const float4*)(vsum + (b * 10 + j) * 16 + q * 4);
        vs[j][0] = t.x; vs[j][1] = t.y; vs[j][2] = t.z; vs[j][3] = t.w;
    }
    float acc[10][4];
#pragma unroll
    for (int j = 0; j < 10; ++j)
#pragma unroll
        for (int t = 0; t < 4; ++t) acc[j][t] = 0.f;

    const int ib = chunk * 576 + wv * 16 + ig;
    for (int ps = 0; ps < 9; ++ps) {
        const int i = ib + ps * 64;
        const __half* hp = uh + (((long)b * 32256 + i) * 4 + q) * 40;
        uint4 r0 = *(const uint4*)(hp);
        uint4 r1 = *(const uint4*)(hp + 8);
        uint4 r2 = *(const uint4*)(hp + 16);
        uint4 r3 = *(const uint4*)(hp + 24);
        uint4 r4 = *(const uint4*)(hp + 32);
        float uhf[10][4];
        {
            const uint4 rr[5] = {r0, r1, r2, r3, r4};
#pragma unroll
            for (int vv = 0; vv < 5; ++vv) {
                const unsigned wds[4] = {rr[vv].x, rr[vv].y, rr[vv].z, rr[vv].w};
#pragma unroll
                for (int h2 = 0; h2 < 4; ++h2) {
                    const __half2 hh = *(const __half2*)&wds[h2];
                    const int j  = vv * 2 + (h2 >> 1);
                    const int d0 = (h2 & 1) * 2;
                    uhf[j][d0 + 0] = __low2float(hh);
                    uhf[j][d0 + 1] = __high2float(hh);
                }
            }
        }
        float logit[10];
#pragma unroll
        for (int j = 0; j < 10; ++j) {
            float lg = vs[j][0] * uhf[j][0] + vs[j][1] * uhf[j][1]
                     + vs[j][2] * uhf[j][2] + vs[j][3] * uhf[j][3];
            lg += __shfl_xor(lg, 1);
            lg += __shfl_xor(lg, 2);
            logit[j] = lg;
        }
        float mx = logit[0];
#pragma unroll
        for (int j = 1; j < 10; ++j) mx = fmaxf(mx, logit[j]);
        float den = 0.f, e[10];
#pragma unroll
        for (int j = 0; j < 10; ++j) { e[j] = __expf(logit[j] - mx); den += e[j]; }
        const float inv = __builtin_amdgcn_rcpf(den);
#pragma unroll
        for (int j = 0; j < 10; ++j) {
            const float c = e[j] * inv;
#pragma unroll
            for (int t = 0; t < 4; ++t) acc[j][t] = fmaf(c, uhf[j][t], acc[j][t]);
        }
    }
    // reduce the 16 capsule-slots of this wave, then one atomic per (j,t) from lanes 0..3
#pragma unroll
    for (int j = 0; j < 10; ++j)
#pragma unroll
        for (int t = 0; t < 4; ++t) {
            float v2 = acc[j][t];
            v2 += __shfl_xor(v2, 4);
            v2 += __shfl_xor(v2, 8);
            v2 += __shfl_xor(v2, 16);
            v2 += __shfl_xor(v2, 32);
            if (lane < 4) atomicAdd(&sp[(b * 10 + j) * 16 + q * 4 + t], v2);
        }
}

// ---------------------------------------------------------------- v = squash(s); vsum += v
__global__ void k_finish(const float* __restrict__ sp, float* __restrict__ vsum,
                         float* __restrict__ out, const int fin)
{
    const int t = threadIdx.x;
    if (t >= 160) return;          // t = b*10 + j
    const float* s = sp + t * 16;
    float sv[16]; float sq = 0.f;
#pragma unroll
    for (int d = 0; d < 16; ++d) { sv[d] = s[d]; sq += sv[d] * sv[d]; }
    const float sc = sq / ((1.f + sq) * sqrtf(sq + 1e-7f));
    if (fin) {
#pragma unroll
        for (int d = 0; d < 16; ++d) out[t * 16 + d] = sv[d] * sc;
    } else {
        float* vp = vsum + t * 16;
#pragma unroll
        for (int d = 0; d < 16; ++d) vp[d] += sv[d] * sc;
    }
}

extern "C" void kernel_launch(void* const* d_in, const int* in_sizes, int n_in,
                              void* d_out, int out_size, void* d_ws, size_t ws_size,
                              hipStream_t stream)
{
    const float* x   = (const float*)d_in[0];
    const float* c1w = (const float*)d_in[1];
    const float* c1b = (const float*)d_in[2];
    const float* pcw = (const float*)d_in[3];
    const float* pcb = (const float*)d_in[4];
    const float* cW  = (const float*)d_in[5];
    float* out = (float*)d_out;

    // Workspace layout (uh overlaps y/wt/p1/p2, which are dead by the time
    // k_uhat runs). Peak use: 181,706,752 B.
    char* ws = (char*)d_ws;
    float* p0 = (float*)(ws);                                   // 16,515,072 B (u lives here after k_squash)
    __hip_bfloat16* y  = (__hip_bfloat16*)(ws + 16515072);      // 42,205,184 B
    __hip_bfloat16* wt = (__hip_bfloat16*)(ws + 58720256);      // 10,616,832 B
    float* p1 = (float*)(ws + 69337088);                        // 16,515,072 B
    float* p2 = (float*)(ws + 85852160);                        // 16,515,072 B
    __half* uh = (__half*)(ws + 16515072);                      // 165,150,720 B (clobbers y/wt/p1/p2)
    float* sp   = (float*)(ws + 181665792);                     // 3*2560*4 B
    float* vsum = (float*)(ws + 181696512);                     // 2560*4 B

    // zero s-partials + vsum (ws is poisoned 0xAA before every call)
    hipMemsetAsync(sp, 0, (3 * 2560 + 2560) * 4, stream);

    k_conv1<<<16 * 92, 256, 0, stream>>>(x, c1w, c1b, y);
    k_wt<<<20736, 256, 0, stream>>>(pcw, wt);
    k_pcconv<<<dim3(126, 2, 3), 256, 0, stream>>>(y, wt, p0, p1, p2);
    k_squash<<<2016, 256, 0, stream>>>(p0, p1, p2, pcb, p0);   // u in-place into p0
    k_uhat<<<504, 256, 0, stream>>>(p0, cW, uh);
    for (int it = 0; it < 3; ++it) {
        k_route2<<<896, 256, 0, stream>>>(uh, vsum, sp + it * 2560);
        k_finish<<<1, 256, 0, stream>>>(sp + it * 2560, vsum, out, it == 2 ? 1 : 0);
    }
}